// Round 1
// baseline (716.119 us; speedup 1.0000x reference)
//
#include <hip/hip_runtime.h>

typedef __attribute__((ext_vector_type(8))) unsigned short u16x8;
typedef __attribute__((ext_vector_type(4))) unsigned short u16x4;
typedef __attribute__((ext_vector_type(8))) short s16x8;
typedef __attribute__((ext_vector_type(4))) float f32x4;

#define D_MODEL 1024
#define NROWS 32768
#define BM 128
#define BN 128
#define BK 64

__device__ __forceinline__ unsigned short f2bf(float f) {
  union { float f; unsigned int u; } c; c.f = f;
  unsigned int r = (c.u + 0x7fffu + ((c.u >> 16) & 1u)) >> 16;
  return (unsigned short)r;
}
__device__ __forceinline__ float bf2f(unsigned short h) {
  union { unsigned int u; float f; } c; c.u = ((unsigned int)h) << 16;
  return c.f;
}

// async global->LDS, 16B per lane. lds dest must be wave-uniform base (+lane*16 implicit).
__device__ __forceinline__ void gload_lds16(const void* gsrc, void* ldst) {
  const __attribute__((address_space(1))) void* g =
      reinterpret_cast<const __attribute__((address_space(1))) void*>(
          reinterpret_cast<unsigned long long>(gsrc));
  __attribute__((address_space(3))) void* l =
      reinterpret_cast<__attribute__((address_space(3))) void*>(
          static_cast<unsigned int>(reinterpret_cast<unsigned long long>(ldst)));
  __builtin_amdgcn_global_load_lds(g, l, 16, 0, 0);
}

// ---------- weight transpose + convert: W (1024x1024 fp32, KxN) -> WT (NxK bf16) ----------
__global__ __launch_bounds__(256) void wtrans_kernel(
    const float* __restrict__ W0, const float* __restrict__ W1,
    const float* __restrict__ W2, const float* __restrict__ W3,
    unsigned short* __restrict__ T0, unsigned short* __restrict__ T1,
    unsigned short* __restrict__ T2, unsigned short* __restrict__ T3) {
  const float* W = blockIdx.z == 0 ? W0 : blockIdx.z == 1 ? W1 : blockIdx.z == 2 ? W2 : W3;
  unsigned short* T = blockIdx.z == 0 ? T0 : blockIdx.z == 1 ? T1 : blockIdx.z == 2 ? T2 : T3;
  __shared__ float tile[32][33];
  const int tx = threadIdx.x & 31, ty = threadIdx.x >> 5;
  const int n0 = blockIdx.x * 32, k0 = blockIdx.y * 32;
#pragma unroll
  for (int i = 0; i < 4; ++i)
    tile[ty + 8 * i][tx] = W[(size_t)(k0 + ty + 8 * i) * D_MODEL + n0 + tx];
  __syncthreads();
#pragma unroll
  for (int i = 0; i < 4; ++i)
    T[(size_t)(n0 + ty + 8 * i) * D_MODEL + k0 + tx] = f2bf(tile[tx][ty + 8 * i]);
}

// ---------- shared GEMM body: C[M=..,N=1024] = A[*,1024] @ WT^T + bias ----------
// A_FP32: A is fp32, reg-staged with convert into padded LDS. else: bf16 A via global_load_lds.
// OUT_BF16: store bf16, else fp32.
template <bool A_FP32, bool OUT_BF16>
__device__ __forceinline__ void gemm_body(const void* __restrict__ Ap,
                                          const unsigned short* __restrict__ BT,
                                          const float* __restrict__ bias,
                                          void* __restrict__ Cp,
                                          unsigned short* As, unsigned short* Bs) {
  constexpr int AST = A_FP32 ? 72 : 64;  // padded stride for reg-staged A (bank-conflict fix)
  const int tid = threadIdx.x;
  const int lane = tid & 63, wid = tid >> 6;
  const int wr = wid >> 1, wc = wid & 1;          // 2x2 waves of 64x64
  const int mbase = blockIdx.y * BM;
  const int nbase = blockIdx.x * BN;
  const int lrow = lane & 15, lkg = lane >> 4;

  f32x4 zero = {0.f, 0.f, 0.f, 0.f};
  f32x4 acc[4][4];
#pragma unroll
  for (int i = 0; i < 4; ++i)
#pragma unroll
    for (int j = 0; j < 4; ++j) acc[i][j] = zero;

#pragma unroll 1
  for (int kk = 0; kk < D_MODEL; kk += BK) {
    // ---- stage A tile (BM x BK) ----
    if constexpr (A_FP32) {
      const float* A = (const float*)Ap;
#pragma unroll
      for (int q = 0; q < 8; ++q) {
        int c = q * 256 + tid;                 // float4 chunk id
        int row = c >> 4, col = (c & 15) * 4;  // 16 float4 per row
        f32x4 f = *(const f32x4*)(A + (size_t)(mbase + row) * D_MODEL + kk + col);
        u16x4 h;
        h[0] = f2bf(f[0]); h[1] = f2bf(f[1]); h[2] = f2bf(f[2]); h[3] = f2bf(f[3]);
        *(u16x4*)&As[row * AST + col] = h;
      }
    } else {
      const unsigned short* A = (const unsigned short*)Ap;
#pragma unroll
      for (int i = 0; i < 4; ++i) {
        int c = i * 256 + tid;                // 16B chunk id
        int row = c >> 3, col = (c & 7) * 8;
        gload_lds16(A + (size_t)(mbase + row) * D_MODEL + kk + col,
                    &As[(i * 256 + wid * 64) * 8]);
      }
    }
    // ---- stage B tile (BN x BK) from WT (NxK) ----
#pragma unroll
    for (int i = 0; i < 4; ++i) {
      int c = i * 256 + tid;
      int row = c >> 3, col = (c & 7) * 8;
      gload_lds16(BT + (size_t)(nbase + row) * D_MODEL + kk + col,
                  &Bs[(i * 256 + wid * 64) * 8]);
    }
    __syncthreads();
    // ---- compute ----
#pragma unroll
    for (int ks = 0; ks < 2; ++ks) {
      s16x8 af[4], bfr[4];
#pragma unroll
      for (int f = 0; f < 4; ++f) {
        int ar = wr * 64 + f * 16 + lrow;
        af[f] = *(const s16x8*)&As[ar * AST + ks * 32 + lkg * 8];
        int br = wc * 64 + f * 16 + lrow;
        bfr[f] = *(const s16x8*)&Bs[br * 64 + ks * 32 + lkg * 8];
      }
#pragma unroll
      for (int fm = 0; fm < 4; ++fm)
#pragma unroll
        for (int fn = 0; fn < 4; ++fn)
          acc[fm][fn] = __builtin_amdgcn_mfma_f32_16x16x32_bf16(af[fm], bfr[fn], acc[fm][fn], 0, 0, 0);
    }
    __syncthreads();
  }
  // ---- epilogue: C[row][col], col = lane&15, row = (lane>>4)*4 + r (m89-verified layout) ----
  const int crow0 = mbase + wr * 64, ccol0 = nbase + wc * 64;
#pragma unroll
  for (int fm = 0; fm < 4; ++fm) {
#pragma unroll
    for (int fn = 0; fn < 4; ++fn) {
      int col = ccol0 + fn * 16 + lrow;
      float bv = bias[col];
#pragma unroll
      for (int r = 0; r < 4; ++r) {
        int row = crow0 + fm * 16 + lkg * 4 + r;
        float v = acc[fm][fn][r] + bv;
        if constexpr (OUT_BF16)
          ((unsigned short*)Cp)[(size_t)row * D_MODEL + col] = f2bf(v);
        else
          ((float*)Cp)[(size_t)row * D_MODEL + col] = v;
      }
    }
  }
}

__global__ __launch_bounds__(256) void qkv_gemm(
    const float* __restrict__ Xq, const float* __restrict__ Xk, const float* __restrict__ Xv,
    const unsigned short* __restrict__ WqT, const unsigned short* __restrict__ WkT,
    const unsigned short* __restrict__ WvT,
    const float* __restrict__ bq, const float* __restrict__ bk, const float* __restrict__ bv,
    unsigned short* __restrict__ Qb, unsigned short* __restrict__ Kb,
    unsigned short* __restrict__ Vb) {
  __shared__ __align__(16) unsigned short As[128 * 72];
  __shared__ __align__(16) unsigned short Bs[128 * 64];
  const int z = blockIdx.z;
  const float* A = z == 0 ? Xq : z == 1 ? Xk : Xv;
  const unsigned short* BT = z == 0 ? WqT : z == 1 ? WkT : WvT;
  const float* bias = z == 0 ? bq : z == 1 ? bk : bv;
  unsigned short* C = z == 0 ? Qb : z == 1 ? Kb : Vb;
  gemm_body<true, true>(A, BT, bias, C, As, Bs);
}

__global__ __launch_bounds__(256) void out_gemm(
    const unsigned short* __restrict__ Ob, const unsigned short* __restrict__ WoT,
    const float* __restrict__ bo, float* __restrict__ out) {
  __shared__ __align__(16) unsigned short As[128 * 72];
  __shared__ __align__(16) unsigned short Bs[128 * 64];
  gemm_body<false, false>(Ob, WoT, bo, out, As, Bs);
}

// ---------- per-row 16-head attention: one wave per batch row ----------
__global__ __launch_bounds__(256) void attn_kernel(
    const unsigned short* __restrict__ Qb, const unsigned short* __restrict__ Kb,
    const unsigned short* __restrict__ Vb, unsigned short* __restrict__ Ob) {
  __shared__ __align__(16) unsigned short sm[4][3][16 * 72];  // q,k,v padded rows (72)
  const int tid = threadIdx.x, lane = tid & 63, wid = tid >> 6;
  const size_t row = (size_t)blockIdx.x * 4 + wid;
  const unsigned short* srcs[3] = {Qb + row * 1024, Kb + row * 1024, Vb + row * 1024};
#pragma unroll
  for (int m = 0; m < 3; ++m) {
#pragma unroll
    for (int i = 0; i < 2; ++i) {
      int c = lane * 2 + i;  // 128 chunks of 8 elems
      int h = c >> 3, col = (c & 7) * 8;
      *(u16x8*)&sm[wid][m][h * 72 + col] = *(const u16x8*)(srcs[m] + h * 64 + col);
    }
  }
  __syncthreads();

  const int h = lane & 15, gq = lane >> 4;  // this lane: head h, g-block gq (4 g's)
  float s[4] = {0.f, 0.f, 0.f, 0.f};
#pragma unroll
  for (int dc = 0; dc < 8; ++dc) {
    u16x8 qv = *(const u16x8*)&sm[wid][0][h * 72 + dc * 8];
    float qf[8];
#pragma unroll
    for (int e = 0; e < 8; ++e) qf[e] = bf2f(qv[e]);
#pragma unroll
    for (int j = 0; j < 4; ++j) {
      u16x8 kv = *(const u16x8*)&sm[wid][1][(gq * 4 + j) * 72 + dc * 8];
#pragma unroll
      for (int e = 0; e < 8; ++e) s[j] += qf[e] * bf2f(kv[e]);
    }
  }
  // softmax over g (scale 1/sqrt(64)=0.125); values spread over lanes h, h+16, h+32, h+48
  float mx = s[0];
#pragma unroll
  for (int j = 0; j < 4; ++j) { s[j] *= 0.125f; mx = fmaxf(mx * (j == 0 ? 0.125f : 1.f), s[j]); }
  mx = fmaxf(mx, __shfl_xor(mx, 16, 64));
  mx = fmaxf(mx, __shfl_xor(mx, 32, 64));
  float p[4], sum = 0.f;
#pragma unroll
  for (int j = 0; j < 4; ++j) { p[j] = __expf(s[j] - mx); sum += p[j]; }
  sum += __shfl_xor(sum, 16, 64);
  sum += __shfl_xor(sum, 32, 64);
  const float rinv = 1.0f / sum;
  // broadcast all 16 p's for this head to the 4 lanes owning it
  float pall[16];
#pragma unroll
  for (int t = 0; t < 4; ++t)
#pragma unroll
    for (int j = 0; j < 4; ++j) pall[t * 4 + j] = __shfl(p[j], h + 16 * t, 64);
  // PV: this lane produces o[h][gq*16 .. +16)
  float o[16];
#pragma unroll
  for (int e = 0; e < 16; ++e) o[e] = 0.f;
  const int db = gq * 16;
#pragma unroll
  for (int g = 0; g < 16; ++g) {
    float pg = pall[g];
    u16x8 v0 = *(const u16x8*)&sm[wid][2][g * 72 + db];
    u16x8 v1 = *(const u16x8*)&sm[wid][2][g * 72 + db + 8];
#pragma unroll
    for (int e = 0; e < 8; ++e) { o[e] += pg * bf2f(v0[e]); o[8 + e] += pg * bf2f(v1[e]); }
  }
  u16x8 r0, r1;
#pragma unroll
  for (int e = 0; e < 8; ++e) { r0[e] = f2bf(o[e] * rinv); r1[e] = f2bf(o[8 + e] * rinv); }
  unsigned short* dst = Ob + row * 1024 + h * 64 + db;
  *(u16x8*)dst = r0;
  *(u16x8*)(dst + 8) = r1;
}

extern "C" void kernel_launch(void* const* d_in, const int* in_sizes, int n_in,
                              void* d_out, int out_size, void* d_ws, size_t ws_size,
                              hipStream_t stream) {
  const float* queries = (const float*)d_in[0];
  const float* keys    = (const float*)d_in[1];
  const float* values  = (const float*)d_in[2];
  const float* Wq = (const float*)d_in[3];
  const float* bq = (const float*)d_in[4];
  const float* Wk = (const float*)d_in[5];
  const float* bk = (const float*)d_in[6];
  const float* Wv = (const float*)d_in[7];
  const float* bv = (const float*)d_in[8];
  const float* Wo = (const float*)d_in[9];
  const float* bo = (const float*)d_in[10];
  float* out = (float*)d_out;

  unsigned short* ws = (unsigned short*)d_ws;
  const size_t WELEM = (size_t)1024 * 1024;     // 1M elems (2MB bf16)
  const size_t XELEM = (size_t)NROWS * 1024;    // 32M elems (64MB bf16)
  unsigned short* WqT = ws;
  unsigned short* WkT = WqT + WELEM;
  unsigned short* WvT = WkT + WELEM;
  unsigned short* WoT = WvT + WELEM;
  unsigned short* Qb = WoT + WELEM;
  unsigned short* Kb = Qb + XELEM;
  unsigned short* Vb = Kb + XELEM;
  unsigned short* Ob = Vb + XELEM;
  // total ws use: 8MB + 256MB

  wtrans_kernel<<<dim3(32, 32, 4), 256, 0, stream>>>(Wq, Wk, Wv, Wo, WqT, WkT, WvT, WoT);
  qkv_gemm<<<dim3(D_MODEL / BN, NROWS / BM, 3), 256, 0, stream>>>(
      queries, keys, values, WqT, WkT, WvT, bq, bk, bv, Qb, Kb, Vb);
  attn_kernel<<<dim3(NROWS / 4), 256, 0, stream>>>(Qb, Kb, Vb, Ob);
  out_gemm<<<dim3(D_MODEL / BN, NROWS / BM, 1), 256, 0, stream>>>(Ob, WoT, bo, out);
}

// Round 2
// 486.156 us; speedup vs baseline: 1.4730x; 1.4730x over previous
//
#include <hip/hip_runtime.h>

typedef __attribute__((ext_vector_type(8))) unsigned short u16x8;
typedef __attribute__((ext_vector_type(8))) short s16x8;
typedef __attribute__((ext_vector_type(4))) float f32x4;

#define D_MODEL 1024
#define NROWS 32768
#define BK 64
#define NT 16  // K-tiles = 1024/64

__device__ __forceinline__ unsigned short f2bf(float f) {
  union { float f; unsigned int u; } c; c.f = f;
  return (unsigned short)((c.u + 0x7fffu + ((c.u >> 16) & 1u)) >> 16);
}
__device__ __forceinline__ float bf2f(unsigned short h) {
  union { unsigned int u; float f; } c; c.u = ((unsigned int)h) << 16;
  return c.f;
}

// async global->LDS, 16B per lane; lds dest is wave-uniform base (+lane*16 implicit)
__device__ __forceinline__ void gload_lds16(const void* gsrc, void* ldst) {
  const __attribute__((address_space(1))) void* g =
      reinterpret_cast<const __attribute__((address_space(1))) void*>(
          reinterpret_cast<unsigned long long>(gsrc));
  __attribute__((address_space(3))) void* l =
      reinterpret_cast<__attribute__((address_space(3))) void*>(
          static_cast<unsigned int>(reinterpret_cast<unsigned long long>(ldst)));
  __builtin_amdgcn_global_load_lds(g, l, 16, 0, 0);
}

#define BAR() asm volatile("s_barrier" ::: "memory")

// ---------- weight transpose + convert: W (1024x1024 fp32, KxN) -> WT (NxK bf16) ----------
__global__ __launch_bounds__(256) void wtrans_kernel(
    const float* __restrict__ W0, const float* __restrict__ W1,
    const float* __restrict__ W2, const float* __restrict__ W3,
    unsigned short* __restrict__ T0, unsigned short* __restrict__ T1,
    unsigned short* __restrict__ T2, unsigned short* __restrict__ T3) {
  const float* W = blockIdx.z == 0 ? W0 : blockIdx.z == 1 ? W1 : blockIdx.z == 2 ? W2 : W3;
  unsigned short* T = blockIdx.z == 0 ? T0 : blockIdx.z == 1 ? T1 : blockIdx.z == 2 ? T2 : T3;
  __shared__ float tile[32][33];
  const int tx = threadIdx.x & 31, ty = threadIdx.x >> 5;
  const int n0 = blockIdx.x * 32, k0 = blockIdx.y * 32;
#pragma unroll
  for (int i = 0; i < 4; ++i)
    tile[ty + 8 * i][tx] = W[(size_t)(k0 + ty + 8 * i) * D_MODEL + n0 + tx];
  __syncthreads();
#pragma unroll
  for (int i = 0; i < 4; ++i)
    T[(size_t)(n0 + ty + 8 * i) * D_MODEL + k0 + tx] = f2bf(tile[tx][ty + 8 * i]);
}

// ---------- fp32 -> bf16 convert for the three activation matrices ----------
__global__ __launch_bounds__(256) void xconvert(
    const float* __restrict__ X0, const float* __restrict__ X1, const float* __restrict__ X2,
    unsigned short* __restrict__ Y0, unsigned short* __restrict__ Y1,
    unsigned short* __restrict__ Y2) {
  const float* X = blockIdx.z == 0 ? X0 : blockIdx.z == 1 ? X1 : X2;
  unsigned short* Y = blockIdx.z == 0 ? Y0 : blockIdx.z == 1 ? Y1 : Y2;
  const int NCH = (NROWS * D_MODEL) / 8;
  for (int c = blockIdx.x * 256 + threadIdx.x; c < NCH; c += gridDim.x * 256) {
    f32x4 f0 = *(const f32x4*)(X + (size_t)c * 8);
    f32x4 f1 = *(const f32x4*)(X + (size_t)c * 8 + 4);
    u16x8 h;
#pragma unroll
    for (int e = 0; e < 4; ++e) { h[e] = f2bf(f0[e]); h[4 + e] = f2bf(f1[e]); }
    *(u16x8*)(Y + (size_t)c * 8) = h;
  }
}

// ---------- 256x256 8-phase bf16 GEMM: C[M,1024] = A[M,1024] @ BT^T + bias ----------
// 512 threads = 8 waves (2M x 4N), BK=64, LDS 128KiB double-buffered, T2 swizzle,
// counted vmcnt (T4), setprio around MFMA (T5), XCD-swizzled blockIdx (T1).
#define MFMA16(p, A00, A01, A10, A11)                                                        \
  _Pragma("unroll") for (int n = 0; n < 4; ++n) {                                            \
    acc[2*(p)][n]   = __builtin_amdgcn_mfma_f32_16x16x32_bf16(A00, bfr[n][0], acc[2*(p)][n], 0, 0, 0);   \
    acc[2*(p)][n]   = __builtin_amdgcn_mfma_f32_16x16x32_bf16(A01, bfr[n][1], acc[2*(p)][n], 0, 0, 0);   \
    acc[2*(p)+1][n] = __builtin_amdgcn_mfma_f32_16x16x32_bf16(A10, bfr[n][0], acc[2*(p)+1][n], 0, 0, 0); \
    acc[2*(p)+1][n] = __builtin_amdgcn_mfma_f32_16x16x32_bf16(A11, bfr[n][1], acc[2*(p)+1][n], 0, 0, 0); \
  }

#define LDA_(Ac, m, ksoff) (*(const s16x8*)((Ac) + (wm * 128 + (m) * 16 + lrow) * 128 + (ksoff)))
#define LDB_(Bc, n, ksoff) (*(const s16x8*)((Bc) + (wn * 64 + (n) * 16 + lrow) * 128 + (ksoff)))

template <bool OUT_BF16>
__device__ __forceinline__ void gemm8p_body(
    const unsigned short* __restrict__ A, const unsigned short* __restrict__ BT,
    const float* __restrict__ bias, void* __restrict__ Cp, char* smem) {
  const int tid = threadIdx.x;
  const int lane = tid & 63, wid = tid >> 6;
  const int wm = wid >> 2, wn = wid & 3;          // 2x4 waves, each owns 128x64 of C
  const int lrow = lane & 15, lkg = lane >> 4;

  // XCD-aware bijective swizzle: nwg = 4*128 = 512, 512 % 8 == 0
  const int id = blockIdx.y * gridDim.x + blockIdx.x;
  const int sw = (id & 7) * 64 + (id >> 3);
  const int mbase = (sw >> 2) * 256;
  const int nbase = (sw & 3) * 256;

  char* const Ab0 = smem;
  char* const Ab1 = smem + 32768;
  char* const Bb0 = smem + 65536;
  char* const Bb1 = smem + 98304;

  // staging: linear LDS dest; inverse-swizzled global source (rule #21)
  const int sgoff = (((tid & 7) ^ ((tid >> 3) & 7)) * 8);  // element offset in row
  const int srow = tid >> 3;                               // row within 64-row chunk
  // read-side swizzled 16B-slot byte offsets per k-step: slot = (ks*4+lkg) ^ (row&7)
  const int soff0 = ((0 + lkg) ^ (lrow & 7)) * 16;
  const int soff1 = ((4 + lkg) ^ (lrow & 7)) * 16;
  const int ldsw = wid * 1024;

  auto stA = [&](int u, int half) {
    const unsigned short* G =
        A + (size_t)(mbase + half * 128 + srow) * D_MODEL + u * BK + sgoff;
    char* L = ((u & 1) ? Ab1 : Ab0) + half * 16384 + ldsw;
    gload_lds16(G, L);
    gload_lds16(G + (size_t)64 * D_MODEL, L + 8192);
  };
  auto stB = [&](int u, int half) {
    const unsigned short* G =
        BT + (size_t)(nbase + half * 128 + srow) * D_MODEL + u * BK + sgoff;
    char* L = ((u & 1) ? Bb1 : Bb0) + half * 16384 + ldsw;
    gload_lds16(G, L);
    gload_lds16(G + (size_t)64 * D_MODEL, L + 8192);
  };

  f32x4 acc[8][4];
  f32x4 zero = {0.f, 0.f, 0.f, 0.f};
#pragma unroll
  for (int m = 0; m < 8; ++m)
#pragma unroll
    for (int n = 0; n < 4; ++n) acc[m][n] = zero;
  s16x8 bfr[4][2];

  // prologue: tile0 fully + B(1); allow B(1)'s 4 instrs to stay in flight
  stA(0, 0); stA(0, 1); stB(0, 0); stB(0, 1);
  stB(1, 0); stB(1, 1);
  asm volatile("s_waitcnt vmcnt(4)" ::: "memory");
  BAR();

#pragma unroll 1
  for (int u = 0; u < NT; ++u) {
    char* Ac = (u & 1) ? Ab1 : Ab0;
    char* Bc = (u & 1) ? Bb1 : Bb0;
    // ---- phase 0: M-frags 0,1 + all B-frags; stage A.lo(u+1) -> other buf ----
    {
      s16x8 a00 = LDA_(Ac, 0, soff0), a01 = LDA_(Ac, 0, soff1);
      s16x8 a10 = LDA_(Ac, 1, soff0), a11 = LDA_(Ac, 1, soff1);
#pragma unroll
      for (int n = 0; n < 4; ++n) { bfr[n][0] = LDB_(Bc, n, soff0); bfr[n][1] = LDB_(Bc, n, soff1); }
      if (u + 1 < NT) stA(u + 1, 0);
      BAR();
      __builtin_amdgcn_s_setprio(1);
      MFMA16(0, a00, a01, a10, a11);
      __builtin_amdgcn_s_setprio(0);
      BAR();
    }
    // ---- phase 1: M-frags 2,3; stage A.hi(u+1) ----
    {
      s16x8 a00 = LDA_(Ac, 2, soff0), a01 = LDA_(Ac, 2, soff1);
      s16x8 a10 = LDA_(Ac, 3, soff0), a11 = LDA_(Ac, 3, soff1);
      if (u + 1 < NT) stA(u + 1, 1);
      BAR();
      __builtin_amdgcn_s_setprio(1);
      MFMA16(1, a00, a01, a10, a11);
      __builtin_amdgcn_s_setprio(0);
      BAR();
    }
    // ---- phase 2: M-frags 4,5; stage B.lo(u+2) -> current buf (B reads done in ph0) ----
    {
      s16x8 a00 = LDA_(Ac, 4, soff0), a01 = LDA_(Ac, 4, soff1);
      s16x8 a10 = LDA_(Ac, 5, soff0), a11 = LDA_(Ac, 5, soff1);
      if (u + 2 < NT) stB(u + 2, 0);
      BAR();
      __builtin_amdgcn_s_setprio(1);
      MFMA16(2, a00, a01, a10, a11);
      __builtin_amdgcn_s_setprio(0);
      BAR();
    }
    // ---- phase 3: M-frags 6,7; stage B.hi(u+2); counted vmcnt gates tile u+1 ----
    {
      s16x8 a00 = LDA_(Ac, 6, soff0), a01 = LDA_(Ac, 6, soff1);
      s16x8 a10 = LDA_(Ac, 7, soff0), a11 = LDA_(Ac, 7, soff1);
      if (u + 2 < NT) {
        stB(u + 2, 1);
        asm volatile("s_waitcnt vmcnt(4)" ::: "memory");  // keep B(u+2)'s 4 in flight
      } else {
        asm volatile("s_waitcnt vmcnt(0)" ::: "memory");  // tail: drain
      }
      BAR();
      __builtin_amdgcn_s_setprio(1);
      MFMA16(3, a00, a01, a10, a11);
      __builtin_amdgcn_s_setprio(0);
      BAR();
    }
  }

  // ---- epilogue: C layout col=lane&15, row=(lane>>4)*4+r (m89-verified) ----
  const size_t crow0 = mbase + wm * 128;
  const int ccol0 = nbase + wn * 64;
#pragma unroll
  for (int m = 0; m < 8; ++m) {
#pragma unroll
    for (int n = 0; n < 4; ++n) {
      const int col = ccol0 + n * 16 + lrow;
      const float bv = bias[col];
#pragma unroll
      for (int r = 0; r < 4; ++r) {
        const size_t row = crow0 + m * 16 + lkg * 4 + r;
        const float v = acc[m][n][r] + bv;
        if constexpr (OUT_BF16)
          ((unsigned short*)Cp)[row * D_MODEL + col] = f2bf(v);
        else
          ((float*)Cp)[row * D_MODEL + col] = v;
      }
    }
  }
}

__global__ __launch_bounds__(512, 1) void qkv_gemm8(
    const unsigned short* __restrict__ Xq, const unsigned short* __restrict__ Xk,
    const unsigned short* __restrict__ Xv,
    const unsigned short* __restrict__ WqT, const unsigned short* __restrict__ WkT,
    const unsigned short* __restrict__ WvT,
    const float* __restrict__ bq, const float* __restrict__ bk, const float* __restrict__ bv,
    unsigned short* __restrict__ Qb, unsigned short* __restrict__ Kb,
    unsigned short* __restrict__ Vb) {
  extern __shared__ char smem[];
  const int z = blockIdx.z;
  gemm8p_body<true>(z == 0 ? Xq : z == 1 ? Xk : Xv,
                    z == 0 ? WqT : z == 1 ? WkT : WvT,
                    z == 0 ? bq : z == 1 ? bk : bv,
                    z == 0 ? (void*)Qb : z == 1 ? (void*)Kb : (void*)Vb, smem);
}

__global__ __launch_bounds__(512, 1) void out_gemm8(
    const unsigned short* __restrict__ Ob, const unsigned short* __restrict__ WoT,
    const float* __restrict__ bo, float* __restrict__ out) {
  extern __shared__ char smem[];
  gemm8p_body<false>(Ob, WoT, bo, out, smem);
}

// ---------- per-row 16-head attention: one wave per batch row ----------
__global__ __launch_bounds__(256) void attn_kernel(
    const unsigned short* __restrict__ Qb, const unsigned short* __restrict__ Kb,
    const unsigned short* __restrict__ Vb, unsigned short* __restrict__ Ob) {
  __shared__ __align__(16) unsigned short sm[4][3][16 * 72];
  const int tid = threadIdx.x, lane = tid & 63, wid = tid >> 6;
  const size_t row = (size_t)blockIdx.x * 4 + wid;
  const unsigned short* srcs[3] = {Qb + row * 1024, Kb + row * 1024, Vb + row * 1024};
#pragma unroll
  for (int m = 0; m < 3; ++m) {
#pragma unroll
    for (int i = 0; i < 2; ++i) {
      int c = lane * 2 + i;
      int h = c >> 3, col = (c & 7) * 8;
      *(u16x8*)&sm[wid][m][h * 72 + col] = *(const u16x8*)(srcs[m] + h * 64 + col);
    }
  }
  __syncthreads();

  const int h = lane & 15, gq = lane >> 4;
  float s[4] = {0.f, 0.f, 0.f, 0.f};
#pragma unroll
  for (int dc = 0; dc < 8; ++dc) {
    u16x8 qv = *(const u16x8*)&sm[wid][0][h * 72 + dc * 8];
    float qf[8];
#pragma unroll
    for (int e = 0; e < 8; ++e) qf[e] = bf2f(qv[e]);
#pragma unroll
    for (int j = 0; j < 4; ++j) {
      u16x8 kv = *(const u16x8*)&sm[wid][1][(gq * 4 + j) * 72 + dc * 8];
#pragma unroll
      for (int e = 0; e < 8; ++e) s[j] += qf[e] * bf2f(kv[e]);
    }
  }
  float mx = s[0];
#pragma unroll
  for (int j = 0; j < 4; ++j) { s[j] *= 0.125f; mx = fmaxf(mx * (j == 0 ? 0.125f : 1.f), s[j]); }
  mx = fmaxf(mx, __shfl_xor(mx, 16, 64));
  mx = fmaxf(mx, __shfl_xor(mx, 32, 64));
  float p[4], sum = 0.f;
#pragma unroll
  for (int j = 0; j < 4; ++j) { p[j] = __expf(s[j] - mx); sum += p[j]; }
  sum += __shfl_xor(sum, 16, 64);
  sum += __shfl_xor(sum, 32, 64);
  const float rinv = 1.0f / sum;
  float pall[16];
#pragma unroll
  for (int t = 0; t < 4; ++t)
#pragma unroll
    for (int j = 0; j < 4; ++j) pall[t * 4 + j] = __shfl(p[j], h + 16 * t, 64);
  float o[16];
#pragma unroll
  for (int e = 0; e < 16; ++e) o[e] = 0.f;
  const int db = gq * 16;
#pragma unroll
  for (int g = 0; g < 16; ++g) {
    float pg = pall[g];
    u16x8 v0 = *(const u16x8*)&sm[wid][2][g * 72 + db];
    u16x8 v1 = *(const u16x8*)&sm[wid][2][g * 72 + db + 8];
#pragma unroll
    for (int e = 0; e < 8; ++e) { o[e] += pg * bf2f(v0[e]); o[8 + e] += pg * bf2f(v1[e]); }
  }
  u16x8 r0, r1;
#pragma unroll
  for (int e = 0; e < 8; ++e) { r0[e] = f2bf(o[e] * rinv); r1[e] = f2bf(o[8 + e] * rinv); }
  unsigned short* dst = Ob + row * 1024 + h * 64 + db;
  *(u16x8*)dst = r0;
  *(u16x8*)(dst + 8) = r1;
}

extern "C" void kernel_launch(void* const* d_in, const int* in_sizes, int n_in,
                              void* d_out, int out_size, void* d_ws, size_t ws_size,
                              hipStream_t stream) {
  const float* queries = (const float*)d_in[0];
  const float* keys    = (const float*)d_in[1];
  const float* values  = (const float*)d_in[2];
  const float* Wq = (const float*)d_in[3];
  const float* bq = (const float*)d_in[4];
  const float* Wk = (const float*)d_in[5];
  const float* bk = (const float*)d_in[6];
  const float* Wv = (const float*)d_in[7];
  const float* bv = (const float*)d_in[8];
  const float* Wo = (const float*)d_in[9];
  const float* bo = (const float*)d_in[10];
  float* out = (float*)d_out;

  unsigned short* ws = (unsigned short*)d_ws;
  const size_t WE = (size_t)1024 * 1024;
  const size_t XE = (size_t)NROWS * 1024;
  unsigned short* WqT = ws;
  unsigned short* WkT = WqT + WE;
  unsigned short* WvT = WkT + WE;
  unsigned short* WoT = WvT + WE;
  unsigned short* Xcq = WoT + WE;
  unsigned short* Xck = Xcq + XE;
  unsigned short* Xcv = Xck + XE;
  unsigned short* Qb  = Xcv + XE;
  unsigned short* Kb  = Qb + XE;
  unsigned short* Vb  = Kb + XE;
  unsigned short* Ob  = Xcq;  // alias: Xc* dead after qkv_gemm8
  // ws use: 8 MB weights + 6 x 64 MB = 392 MB

  hipFuncSetAttribute((const void*)qkv_gemm8, hipFuncAttributeMaxDynamicSharedMemorySize, 131072);
  hipFuncSetAttribute((const void*)out_gemm8, hipFuncAttributeMaxDynamicSharedMemorySize, 131072);

  wtrans_kernel<<<dim3(32, 32, 4), 256, 0, stream>>>(Wq, Wk, Wv, Wo, WqT, WkT, WvT, WoT);
  xconvert<<<dim3(2048, 1, 3), 256, 0, stream>>>(queries, keys, values, Xcq, Xck, Xcv);
  qkv_gemm8<<<dim3(4, 128, 3), 512, 131072, stream>>>(
      Xcq, Xck, Xcv, WqT, WkT, WvT, bq, bk, bv, Qb, Kb, Vb);
  attn_kernel<<<dim3(NROWS / 4), 256, 0, stream>>>(Qb, Kb, Vb, Ob);
  out_gemm8<<<dim3(4, 128, 1), 512, 131072, stream>>>(Ob, WoT, bo, out);
}

// Round 3
// 445.097 us; speedup vs baseline: 1.6089x; 1.0922x over previous
//
#include <hip/hip_runtime.h>

typedef __attribute__((ext_vector_type(8))) unsigned short u16x8;
typedef __attribute__((ext_vector_type(8))) short s16x8;
typedef __attribute__((ext_vector_type(4))) float f32x4;

#define D_MODEL 1024
#define NROWS 32768
#define BK 64
#define NT 16  // K-tiles = 1024/64

__device__ __forceinline__ unsigned short f2bf(float f) {
  union { float f; unsigned int u; } c; c.f = f;
  return (unsigned short)((c.u + 0x7fffu + ((c.u >> 16) & 1u)) >> 16);
}
__device__ __forceinline__ float bf2f(unsigned short h) {
  union { unsigned int u; float f; } c; c.u = ((unsigned int)h) << 16;
  return c.f;
}
// packed fp32 pair -> 2x bf16 (RTNE), single VALU op
__device__ __forceinline__ unsigned int cvtpk_bf16(float lo, float hi) {
  unsigned int r;
  asm("v_cvt_pk_bf16_f32 %0, %1, %2" : "=v"(r) : "v"(lo), "v"(hi));
  return r;
}

// async global->LDS, 16B per lane; lds dest is wave-uniform base (+lane*16 implicit)
__device__ __forceinline__ void gload_lds16(const void* gsrc, void* ldst) {
  const __attribute__((address_space(1))) void* g =
      reinterpret_cast<const __attribute__((address_space(1))) void*>(
          reinterpret_cast<unsigned long long>(gsrc));
  __attribute__((address_space(3))) void* l =
      reinterpret_cast<__attribute__((address_space(3))) void*>(
          static_cast<unsigned int>(reinterpret_cast<unsigned long long>(ldst)));
  __builtin_amdgcn_global_load_lds(g, l, 16, 0, 0);
}

#define BAR() asm volatile("s_barrier" ::: "memory")

// ---------- weight transpose + convert: W (1024x1024 fp32, KxN) -> WT (NxK bf16) ----------
__global__ __launch_bounds__(256) void wtrans_kernel(
    const float* __restrict__ W0, const float* __restrict__ W1,
    const float* __restrict__ W2, const float* __restrict__ W3,
    unsigned short* __restrict__ T0, unsigned short* __restrict__ T1,
    unsigned short* __restrict__ T2, unsigned short* __restrict__ T3) {
  const float* W = blockIdx.z == 0 ? W0 : blockIdx.z == 1 ? W1 : blockIdx.z == 2 ? W2 : W3;
  unsigned short* T = blockIdx.z == 0 ? T0 : blockIdx.z == 1 ? T1 : blockIdx.z == 2 ? T2 : T3;
  __shared__ float tile[32][33];
  const int tx = threadIdx.x & 31, ty = threadIdx.x >> 5;
  const int n0 = blockIdx.x * 32, k0 = blockIdx.y * 32;
#pragma unroll
  for (int i = 0; i < 4; ++i)
    tile[ty + 8 * i][tx] = W[(size_t)(k0 + ty + 8 * i) * D_MODEL + n0 + tx];
  __syncthreads();
#pragma unroll
  for (int i = 0; i < 4; ++i)
    T[(size_t)(n0 + ty + 8 * i) * D_MODEL + k0 + tx] = f2bf(tile[tx][ty + 8 * i]);
}

// ---------- 256x256 8-phase bf16 GEMM ----------
// 512 threads = 8 waves (2M x 4N), BK=64, LDS 128KiB double-buffered, T2 swizzle,
// counted vmcnt (T4), setprio (T5), XCD swizzle (T1).
// A_FP32: A read as fp32, reg-staged (T14 split: issue ph0/ph1, cvt+ds_write ph2).
#define MFMA16(p, A00, A01, A10, A11)                                                        \
  _Pragma("unroll") for (int n = 0; n < 4; ++n) {                                            \
    acc[2*(p)][n]   = __builtin_amdgcn_mfma_f32_16x16x32_bf16(A00, bfr[n][0], acc[2*(p)][n], 0, 0, 0);   \
    acc[2*(p)][n]   = __builtin_amdgcn_mfma_f32_16x16x32_bf16(A01, bfr[n][1], acc[2*(p)][n], 0, 0, 0);   \
    acc[2*(p)+1][n] = __builtin_amdgcn_mfma_f32_16x16x32_bf16(A10, bfr[n][0], acc[2*(p)+1][n], 0, 0, 0); \
    acc[2*(p)+1][n] = __builtin_amdgcn_mfma_f32_16x16x32_bf16(A11, bfr[n][1], acc[2*(p)+1][n], 0, 0, 0); \
  }

#define LDA_(Ac, m, ksoff) (*(const s16x8*)((Ac) + (wm * 128 + (m) * 16 + lrow) * 128 + (ksoff)))
#define LDB_(Bc, n, ksoff) (*(const s16x8*)((Bc) + (wn * 64 + (n) * 16 + lrow) * 128 + (ksoff)))

template <bool A_FP32, bool OUT_BF16>
__device__ __forceinline__ void gemm8p_body(
    const void* __restrict__ Ap, const unsigned short* __restrict__ BT,
    const float* __restrict__ bias, void* __restrict__ Cp, char* smem) {
  const int tid = threadIdx.x;
  const int lane = tid & 63, wid = tid >> 6;
  const int wm = wid >> 2, wn = wid & 3;  // 2x4 waves, each owns 128x64 of C
  const int lrow = lane & 15, lkg = lane >> 4;

  // XCD-aware bijective swizzle: nwg per z = 512, 512 % 8 == 0
  const int id = blockIdx.y * gridDim.x + blockIdx.x;
  const int sw = (id & 7) * 64 + (id >> 3);
  const int mbase = (sw >> 2) * 256;
  const int nbase = (sw & 3) * 256;

  char* const Ab0 = smem;
  char* const Ab1 = smem + 32768;
  char* const Bb0 = smem + 65536;
  char* const Bb1 = smem + 98304;

  // gload_lds staging: linear LDS dest; inverse-swizzled global source (rule #21)
  const int sgoff = (((tid & 7) ^ ((tid >> 3) & 7)) * 8);
  const int srow = tid >> 3;
  // read-side swizzled 16B-slot offsets: slot = (ks*4+lkg) ^ (row&7)
  const int soff0 = ((0 + lkg) ^ (lrow & 7)) * 16;
  const int soff1 = ((4 + lkg) ^ (lrow & 7)) * 16;
  const int ldsw = wid * 1024;

  auto stA = [&](int u, int half) {  // bf16-A path only
    const unsigned short* G =
        (const unsigned short*)Ap + (size_t)(mbase + half * 128 + srow) * D_MODEL + u * BK + sgoff;
    char* L = ((u & 1) ? Ab1 : Ab0) + half * 16384 + ldsw;
    gload_lds16(G, L);
    gload_lds16(G + (size_t)64 * D_MODEL, L + 8192);
  };
  auto stB = [&](int u, int half) {
    const unsigned short* G =
        BT + (size_t)(nbase + half * 128 + srow) * D_MODEL + u * BK + sgoff;
    char* L = ((u & 1) ? Bb1 : Bb0) + half * 16384 + ldsw;
    gload_lds16(G, L);
    gload_lds16(G + (size_t)64 * D_MODEL, L + 8192);
  };

  // fp32-A reg staging: plain global source, write-side XOR swizzle on ds_write.
  f32x4 fa[8];
  auto ldA = [&](int u, int half) {  // issue 4 global_load_dwordx4 into regs
    const float* G = (const float*)Ap +
        (size_t)(mbase + half * 128 + srow) * D_MODEL + u * BK + (tid & 7) * 8;
    fa[half * 4 + 0] = *(const f32x4*)G;
    fa[half * 4 + 1] = *(const f32x4*)(G + 4);
    fa[half * 4 + 2] = *(const f32x4*)(G + (size_t)64 * D_MODEL);
    fa[half * 4 + 3] = *(const f32x4*)(G + (size_t)64 * D_MODEL + 4);
  };
  auto wrA = [&](int u) {  // cvt + swizzled ds_write of all 8 chunks
    char* Abuf = ((u & 1) ? Ab1 : Ab0);
#pragma unroll
    for (int h = 0; h < 2; ++h) {
#pragma unroll
      for (int rr = 0; rr < 2; ++rr) {
        f32x4 lo = fa[h * 4 + rr * 2 + 0];
        f32x4 hi = fa[h * 4 + rr * 2 + 1];
        union { unsigned int w[4]; u16x8 v; } pk;
        pk.w[0] = cvtpk_bf16(lo[0], lo[1]);
        pk.w[1] = cvtpk_bf16(lo[2], lo[3]);
        pk.w[2] = cvtpk_bf16(hi[0], hi[1]);
        pk.w[3] = cvtpk_bf16(hi[2], hi[3]);
        const int r = srow + rr * 64;
        *(u16x8*)(Abuf + h * 16384 + r * 128 + (((tid & 7) ^ (r & 7)) * 16)) = pk.v;
      }
    }
    asm volatile("s_waitcnt lgkmcnt(0)" ::: "memory");  // writes visible before phase BAR
  };

  f32x4 acc[8][4];
  f32x4 zero = {0.f, 0.f, 0.f, 0.f};
#pragma unroll
  for (int m = 0; m < 8; ++m)
#pragma unroll
    for (int n = 0; n < 4; ++n) acc[m][n] = zero;
  s16x8 bfr[4][2];

  // ---- prologue ----
  if constexpr (A_FP32) {
    ldA(0, 0); ldA(0, 1);          // 8 reg loads (oldest)
    stB(0, 0); stB(0, 1);          // 4 gloads
    stB(1, 0); stB(1, 1);          // 4 gloads
    asm volatile("s_waitcnt vmcnt(8)" ::: "memory");  // A(0) loads done
    wrA(0);
    asm volatile("s_waitcnt vmcnt(4)" ::: "memory");  // B(0) done, B(1) in flight
  } else {
    stA(0, 0); stA(0, 1); stB(0, 0); stB(0, 1);
    stB(1, 0); stB(1, 1);
    asm volatile("s_waitcnt vmcnt(4)" ::: "memory");
  }
  BAR();

#pragma unroll 1
  for (int u = 0; u < NT; ++u) {
    char* Ac = (u & 1) ? Ab1 : Ab0;
    char* Bc = (u & 1) ? Bb1 : Bb0;
    // ---- phase 0: M-frags 0,1 + all B-frags; issue A(u+1) lo ----
    {
      s16x8 a00 = LDA_(Ac, 0, soff0), a01 = LDA_(Ac, 0, soff1);
      s16x8 a10 = LDA_(Ac, 1, soff0), a11 = LDA_(Ac, 1, soff1);
#pragma unroll
      for (int n = 0; n < 4; ++n) { bfr[n][0] = LDB_(Bc, n, soff0); bfr[n][1] = LDB_(Bc, n, soff1); }
      if (u + 1 < NT) { if constexpr (A_FP32) ldA(u + 1, 0); else stA(u + 1, 0); }
      BAR();
      __builtin_amdgcn_s_setprio(1);
      MFMA16(0, a00, a01, a10, a11);
      __builtin_amdgcn_s_setprio(0);
      BAR();
    }
    // ---- phase 1: M-frags 2,3; issue A(u+1) hi ----
    {
      s16x8 a00 = LDA_(Ac, 2, soff0), a01 = LDA_(Ac, 2, soff1);
      s16x8 a10 = LDA_(Ac, 3, soff0), a11 = LDA_(Ac, 3, soff1);
      if (u + 1 < NT) { if constexpr (A_FP32) ldA(u + 1, 1); else stA(u + 1, 1); }
      BAR();
      __builtin_amdgcn_s_setprio(1);
      MFMA16(1, a00, a01, a10, a11);
      __builtin_amdgcn_s_setprio(0);
      BAR();
    }
    // ---- phase 2: M-frags 4,5; (fp32: drain A-loads, cvt+write); stage B(u+2) lo ----
    {
      s16x8 a00 = LDA_(Ac, 4, soff0), a01 = LDA_(Ac, 4, soff1);
      s16x8 a10 = LDA_(Ac, 5, soff0), a11 = LDA_(Ac, 5, soff1);
      if constexpr (A_FP32) {
        asm volatile("s_waitcnt vmcnt(0)" ::: "memory");  // A(u+1) regs ready (issued 2 phases ago)
        if (u + 1 < NT) wrA(u + 1);
      }
      if (u + 2 < NT) stB(u + 2, 0);
      BAR();
      __builtin_amdgcn_s_setprio(1);
      MFMA16(2, a00, a01, a10, a11);
      __builtin_amdgcn_s_setprio(0);
      BAR();
    }
    // ---- phase 3: M-frags 6,7; stage B(u+2) hi ----
    {
      s16x8 a00 = LDA_(Ac, 6, soff0), a01 = LDA_(Ac, 6, soff1);
      s16x8 a10 = LDA_(Ac, 7, soff0), a11 = LDA_(Ac, 7, soff1);
      if (u + 2 < NT) stB(u + 2, 1);
      if constexpr (!A_FP32) {
        if (u + 2 < NT) {
          asm volatile("s_waitcnt vmcnt(4)" ::: "memory");  // keep B(u+2) in flight
        } else {
          asm volatile("s_waitcnt vmcnt(0)" ::: "memory");
        }
      }
      BAR();
      __builtin_amdgcn_s_setprio(1);
      MFMA16(3, a00, a01, a10, a11);
      __builtin_amdgcn_s_setprio(0);
      BAR();
    }
  }

  // ---- epilogue: C layout col=lane&15, row=(lane>>4)*4+r (m89-verified) ----
  const size_t crow0 = mbase + wm * 128;
  const int ccol0 = nbase + wn * 64;
#pragma unroll
  for (int m = 0; m < 8; ++m) {
#pragma unroll
    for (int n = 0; n < 4; ++n) {
      const int col = ccol0 + n * 16 + lrow;
      const float bv = bias[col];
#pragma unroll
      for (int r = 0; r < 4; ++r) {
        const size_t row = crow0 + m * 16 + lkg * 4 + r;
        const float v = acc[m][n][r] + bv;
        if constexpr (OUT_BF16)
          ((unsigned short*)Cp)[row * D_MODEL + col] = f2bf(v);
        else
          ((float*)Cp)[row * D_MODEL + col] = v;
      }
    }
  }
}

__global__ __launch_bounds__(512, 1) void qkv_gemm8(
    const float* __restrict__ Xq, const float* __restrict__ Xk, const float* __restrict__ Xv,
    const unsigned short* __restrict__ WqT, const unsigned short* __restrict__ WkT,
    const unsigned short* __restrict__ WvT,
    const float* __restrict__ bq, const float* __restrict__ bk, const float* __restrict__ bv,
    unsigned short* __restrict__ Qb, unsigned short* __restrict__ Kb,
    unsigned short* __restrict__ Vb) {
  extern __shared__ char smem[];
  const int z = blockIdx.z;
  gemm8p_body<true, true>(z == 0 ? (const void*)Xq : z == 1 ? (const void*)Xk : (const void*)Xv,
                          z == 0 ? WqT : z == 1 ? WkT : WvT,
                          z == 0 ? bq : z == 1 ? bk : bv,
                          z == 0 ? (void*)Qb : z == 1 ? (void*)Kb : (void*)Vb, smem);
}

__global__ __launch_bounds__(512, 1) void out_gemm8(
    const unsigned short* __restrict__ Ob, const unsigned short* __restrict__ WoT,
    const float* __restrict__ bo, float* __restrict__ out) {
  extern __shared__ char smem[];
  gemm8p_body<false, false>(Ob, WoT, bo, out, smem);
}

// ---------- per-row 16-head attention: one wave per batch row ----------
__global__ __launch_bounds__(256) void attn_kernel(
    const unsigned short* __restrict__ Qb, const unsigned short* __restrict__ Kb,
    const unsigned short* __restrict__ Vb, unsigned short* __restrict__ Ob) {
  __shared__ __align__(16) unsigned short sm[4][3][16 * 72];
  const int tid = threadIdx.x, lane = tid & 63, wid = tid >> 6;
  const size_t row = (size_t)blockIdx.x * 4 + wid;
  const unsigned short* srcs[3] = {Qb + row * 1024, Kb + row * 1024, Vb + row * 1024};
#pragma unroll
  for (int m = 0; m < 3; ++m) {
#pragma unroll
    for (int i = 0; i < 2; ++i) {
      int c = lane * 2 + i;
      int h = c >> 3, col = (c & 7) * 8;
      *(u16x8*)&sm[wid][m][h * 72 + col] = *(const u16x8*)(srcs[m] + h * 64 + col);
    }
  }
  __syncthreads();

  const int h = lane & 15, gq = lane >> 4;
  float s[4] = {0.f, 0.f, 0.f, 0.f};
#pragma unroll
  for (int dc = 0; dc < 8; ++dc) {
    u16x8 qv = *(const u16x8*)&sm[wid][0][h * 72 + dc * 8];
    float qf[8];
#pragma unroll
    for (int e = 0; e < 8; ++e) qf[e] = bf2f(qv[e]);
#pragma unroll
    for (int j = 0; j < 4; ++j) {
      u16x8 kv = *(const u16x8*)&sm[wid][1][(gq * 4 + j) * 72 + dc * 8];
#pragma unroll
      for (int e = 0; e < 8; ++e) s[j] += qf[e] * bf2f(kv[e]);
    }
  }
  float mx = s[0];
#pragma unroll
  for (int j = 0; j < 4; ++j) { s[j] *= 0.125f; mx = fmaxf(mx * (j == 0 ? 0.125f : 1.f), s[j]); }
  mx = fmaxf(mx, __shfl_xor(mx, 16, 64));
  mx = fmaxf(mx, __shfl_xor(mx, 32, 64));
  float p[4], sum = 0.f;
#pragma unroll
  for (int j = 0; j < 4; ++j) { p[j] = __expf(s[j] - mx); sum += p[j]; }
  sum += __shfl_xor(sum, 16, 64);
  sum += __shfl_xor(sum, 32, 64);
  const float rinv = 1.0f / sum;
  float pall[16];
#pragma unroll
  for (int t = 0; t < 4; ++t)
#pragma unroll
    for (int j = 0; j < 4; ++j) pall[t * 4 + j] = __shfl(p[j], h + 16 * t, 64);
  float o[16];
#pragma unroll
  for (int e = 0; e < 16; ++e) o[e] = 0.f;
  const int db = gq * 16;
#pragma unroll
  for (int g = 0; g < 16; ++g) {
    float pg = pall[g];
    u16x8 v0 = *(const u16x8*)&sm[wid][2][g * 72 + db];
    u16x8 v1 = *(const u16x8*)&sm[wid][2][g * 72 + db + 8];
#pragma unroll
    for (int e = 0; e < 8; ++e) { o[e] += pg * bf2f(v0[e]); o[8 + e] += pg * bf2f(v1[e]); }
  }
  u16x8 r0, r1;
#pragma unroll
  for (int e = 0; e < 8; ++e) { r0[e] = f2bf(o[e] * rinv); r1[e] = f2bf(o[8 + e] * rinv); }
  unsigned short* dst = Ob + row * 1024 + h * 64 + db;
  *(u16x8*)dst = r0;
  *(u16x8*)(dst + 8) = r1;
}

extern "C" void kernel_launch(void* const* d_in, const int* in_sizes, int n_in,
                              void* d_out, int out_size, void* d_ws, size_t ws_size,
                              hipStream_t stream) {
  const float* queries = (const float*)d_in[0];
  const float* keys    = (const float*)d_in[1];
  const float* values  = (const float*)d_in[2];
  const float* Wq = (const float*)d_in[3];
  const float* bq = (const float*)d_in[4];
  const float* Wk = (const float*)d_in[5];
  const float* bk = (const float*)d_in[6];
  const float* Wv = (const float*)d_in[7];
  const float* bv = (const float*)d_in[8];
  const float* Wo = (const float*)d_in[9];
  const float* bo = (const float*)d_in[10];
  float* out = (float*)d_out;

  unsigned short* ws = (unsigned short*)d_ws;
  const size_t WE = (size_t)1024 * 1024;
  const size_t XE = (size_t)NROWS * 1024;
  unsigned short* WqT = ws;
  unsigned short* WkT = WqT + WE;
  unsigned short* WvT = WkT + WE;
  unsigned short* WoT = WvT + WE;
  unsigned short* Qb  = WoT + WE;
  unsigned short* Kb  = Qb + XE;
  unsigned short* Vb  = Kb + XE;
  unsigned short* Ob  = Vb + XE;
  // ws use: 8 MB weights + 4 x 64 MB = 264 MB

  hipFuncSetAttribute((const void*)qkv_gemm8, hipFuncAttributeMaxDynamicSharedMemorySize, 131072);
  hipFuncSetAttribute((const void*)out_gemm8, hipFuncAttributeMaxDynamicSharedMemorySize, 131072);

  wtrans_kernel<<<dim3(32, 32, 4), 256, 0, stream>>>(Wq, Wk, Wv, Wo, WqT, WkT, WvT, WoT);
  qkv_gemm8<<<dim3(4, 128, 3), 512, 131072, stream>>>(
      queries, keys, values, WqT, WkT, WvT, bq, bk, bv, Qb, Kb, Vb);
  attn_kernel<<<dim3(NROWS / 4), 256, 0, stream>>>(Qb, Kb, Vb, Ob);
  out_gemm8<<<dim3(4, 128, 1), 512, 131072, stream>>>(Ob, WoT, bo, out);
}